// Round 7
// baseline (214.904 us; speedup 1.0000x reference)
//
#include <hip/hip_runtime.h>
#include <hip/hip_fp16.h>

#define N_NODES 50000
#define N_EDGES 800000
#define F_IN   128
#define F_MID  64
#define F_OUT  40

// ---- counting-sort CSR build ----
#define SLICE_SHIFT 8
#define SLICE_SZ    256                  // nodes per slice (pow2)
#define NSLICE      196                  // ceil(50000/256)
#define PCHUNKS     256                  // edge chunks for bucket passes
#define PCHUNK_E    ((N_EDGES + PCHUNKS - 1) / PCHUNKS)   // 3125
#define NCOUNT      (NSLICE * PCHUNKS)   // 50176

// ---------------- phase A: per-(chunk,slice) counts + global per-slice totals ----------------
// bsum (196 ints) is zeroed by hipMemsetAsync before launch; 256 blocks x 196 atomics
// over 196 addresses = trivial contention. Eliminates the sc_bsum kernel.

__global__ __launch_bounds__(256) void bucket_count(const int* __restrict__ ei,
                                                    int* __restrict__ counts,
                                                    int* __restrict__ bsum) {
    __shared__ int cnt[NSLICE];
    if (threadIdx.x < NSLICE) cnt[threadIdx.x] = 0;
    __syncthreads();
    int e0 = blockIdx.x * PCHUNK_E;
    int e1 = e0 + PCHUNK_E; if (e1 > N_EDGES) e1 = N_EDGES;
    for (int e = e0 + threadIdx.x; e < e1; e += 256) {
        int c = ei[N_EDGES + e];
        atomicAdd(&cnt[c >> SLICE_SHIFT], 1);
    }
    __syncthreads();
    if (threadIdx.x < NSLICE) {
        int v = cnt[threadIdx.x];
        counts[threadIdx.x * PCHUNKS + blockIdx.x] = v;   // slice-major [slice][chunk]
        if (v) atomicAdd(&bsum[threadIdx.x], v);
    }
}

// ---------------- phase B (fused): choff[slice][chunk] in ONE kernel ----------------
// Block b: (1) redundant exclusive scan of bsum (196 slice totals) -> boff_b;
//          (2) exclusive scan of counts row b (256 chunks); choff = sum.
// Replaces sc_bsum + sc_bscan + sc_bscan2.

__global__ __launch_bounds__(256) void sc_scan(const int* __restrict__ counts,
                                               const int* __restrict__ bsum,
                                               int* __restrict__ choff) {
    __shared__ int ws[4];
    __shared__ int sb[256];
    int tid = threadIdx.x, b = blockIdx.x;
    int lane = tid & 63, wv = tid >> 6;

    // (1) exclusive scan of bsum over slices
    int v = (tid < NSLICE) ? bsum[tid] : 0;
    int inc = v;
#pragma unroll
    for (int st = 1; st < 64; st <<= 1) {
        int t = __shfl_up(inc, st, 64);
        if (lane >= st) inc += t;
    }
    if (lane == 63) ws[wv] = inc;
    __syncthreads();
    int woff = 0;
    for (int w = 0; w < wv; ++w) woff += ws[w];
    sb[tid] = woff + inc - v;          // exclusive prefix of slice totals
    __syncthreads();
    int boffb = sb[b];                 // this slice's global base

    // (2) exclusive scan of counts row b over chunks
    int c = counts[b * PCHUNKS + tid];
    inc = c;
#pragma unroll
    for (int st = 1; st < 64; st <<= 1) {
        int t = __shfl_up(inc, st, 64);
        if (lane >= st) inc += t;
    }
    if (lane == 63) ws[wv] = inc;
    __syncthreads();
    woff = 0;
    for (int w = 0; w < wv; ++w) woff += ws[w];
    choff[b * PCHUNKS + tid] = boffb + woff + inc - c;
}

// ---------------- phase C: scatter packed edges into per-(slice,chunk) ranges ----------------

__global__ __launch_bounds__(256) void bucket_scatter(const int* __restrict__ ei,
                                                      const int* __restrict__ choff,
                                                      int* __restrict__ pairs) {
    __shared__ int cur[NSLICE];
    if (threadIdx.x < NSLICE) cur[threadIdx.x] = choff[threadIdx.x * PCHUNKS + blockIdx.x];
    __syncthreads();
    int e0 = blockIdx.x * PCHUNK_E;
    int e1 = e0 + PCHUNK_E; if (e1 > N_EDGES) e1 = N_EDGES;
    for (int e = e0 + threadIdx.x; e < e1; e += 256) {
        int r = ei[e];
        int c = ei[N_EDGES + e];
        int pos = atomicAdd(&cur[c >> SLICE_SHIFT], 1);
        pairs[pos] = r | ((c & (SLICE_SZ - 1)) << 16);
    }
}

// ---------------- phase D: per-slice CSR build (rowptr, dinv, srcs) ----------------

__global__ __launch_bounds__(256) void slice_csr(const int* __restrict__ pairs,
                                                 const int* __restrict__ choff,
                                                 int* __restrict__ rowptr,
                                                 float* __restrict__ dinv,
                                                 int* __restrict__ srcs) {
    __shared__ int hist[SLICE_SZ];
    __shared__ int wpart[4];
    int s = blockIdx.x;
    int base = choff[s * PCHUNKS];
    int end  = (s == NSLICE - 1) ? N_EDGES : choff[(s + 1) * PCHUNKS];
    int tid = threadIdx.x;
    hist[tid] = 0;
    __syncthreads();
    for (int i = base + tid; i < end; i += 256)
        atomicAdd(&hist[pairs[i] >> 16], 1);
    __syncthreads();
    int v = hist[tid];
    int lane = tid & 63, wv = tid >> 6;
    int inc = v;
#pragma unroll
    for (int st = 1; st < 64; st <<= 1) {
        int t = __shfl_up(inc, st, 64);
        if (lane >= st) inc += t;
    }
    if (lane == 63) wpart[wv] = inc;
    __syncthreads();
    int woff = 0;
    for (int w = 0; w < wv; ++w) woff += wpart[w];
    int ex = woff + inc - v;                 // exclusive prefix within slice
    __syncthreads();
    hist[tid] = ex;                          // reuse hist as cursor (own slot only)
    int node = s * SLICE_SZ + tid;
    if (node < N_NODES) {
        rowptr[node] = base + ex;
        dinv[node]   = rsqrtf((float)v + 1.0f);   // +1 = self loop
    }
    if (node == N_NODES - 1) rowptr[N_NODES] = N_EDGES;
    __syncthreads();
    for (int i = base + tid; i < end; i += 256) {
        int p = pairs[i];
        int pos = atomicAdd(&hist[p >> 16], 1);
        srcs[base + pos] = p & 0xFFFF;
    }
}

// ---------------- GEMM1: hw1h = fp16( (x @ W1) * dinv[row] )  (row = 64 halves = 128 B) ----

__global__ __launch_bounds__(256) void gemm1_kernel(const float* __restrict__ x,
                                                    const float* __restrict__ W1,
                                                    const float* __restrict__ dinv,
                                                    __half* __restrict__ hw1h) {
    __shared__ float sW[F_IN * F_MID];   // 32 KB, row-major [k][c]
    __shared__ float sX[64][68];         // 17 KB, one K-half, padded
    int tid = threadIdx.x;
    const float4* W4 = (const float4*)W1;
    float4* sW4 = (float4*)sW;
    for (int i = tid; i < F_IN * F_MID / 4; i += 256) sW4[i] = W4[i];

    int row0 = blockIdx.x * 64;
    int tx = tid & 15, ty = tid >> 4;
    int c0 = tx * 4, r0 = ty * 4;
    float acc[4][4] = {};

    for (int p = 0; p < 2; ++p) {
        __syncthreads();
#pragma unroll
        for (int it = 0; it < 4; ++it) {
            int i = (tid + it * 256) * 4;
            int r = i >> 6, k = i & 63;
            float4 v = make_float4(0.f, 0.f, 0.f, 0.f);
            if (row0 + r < N_NODES)
                v = *(const float4*)&x[(size_t)(row0 + r) * F_IN + p * 64 + k];
            *(float4*)&sX[r][k] = v;
        }
        __syncthreads();
        const float* sWp = sW + p * 64 * F_MID;
#pragma unroll 4
        for (int k = 0; k < 64; ++k) {
            float4 w = *(const float4*)&sWp[k * F_MID + c0];
            float a0 = sX[r0 + 0][k];
            float a1 = sX[r0 + 1][k];
            float a2 = sX[r0 + 2][k];
            float a3 = sX[r0 + 3][k];
            acc[0][0] = fmaf(a0, w.x, acc[0][0]); acc[0][1] = fmaf(a0, w.y, acc[0][1]);
            acc[0][2] = fmaf(a0, w.z, acc[0][2]); acc[0][3] = fmaf(a0, w.w, acc[0][3]);
            acc[1][0] = fmaf(a1, w.x, acc[1][0]); acc[1][1] = fmaf(a1, w.y, acc[1][1]);
            acc[1][2] = fmaf(a1, w.z, acc[1][2]); acc[1][3] = fmaf(a1, w.w, acc[1][3]);
            acc[2][0] = fmaf(a2, w.x, acc[2][0]); acc[2][1] = fmaf(a2, w.y, acc[2][1]);
            acc[2][2] = fmaf(a2, w.z, acc[2][2]); acc[2][3] = fmaf(a2, w.w, acc[2][3]);
            acc[3][0] = fmaf(a3, w.x, acc[3][0]); acc[3][1] = fmaf(a3, w.y, acc[3][1]);
            acc[3][2] = fmaf(a3, w.z, acc[3][2]); acc[3][3] = fmaf(a3, w.w, acc[3][3]);
        }
    }
#pragma unroll
    for (int j = 0; j < 4; ++j) {
        int row = row0 + r0 + j;
        if (row < N_NODES) {
            float d = dinv[row];
            __half2 p0 = __floats2half2_rn(acc[j][0] * d, acc[j][1] * d);
            __half2 p1 = __floats2half2_rn(acc[j][2] * d, acc[j][3] * d);
            uint2 u = make_uint2(*reinterpret_cast<unsigned int*>(&p0),
                                 *reinterpret_cast<unsigned int*>(&p1));
            *reinterpret_cast<uint2*>(&hw1h[(size_t)row * F_MID + c0]) = u;
        }
    }
}

// ---------------- gather1: h = relu(dinv[n]*(sum_e hw1h[src] + hw1h[n]) + b1) ------------
// 16-deep batches: srcs[j..j+15] is one contiguous scalar fetch; 16 row-gathers in
// flight per wave -> deg<=16 nodes (majority) need ONE memory round trip.

__global__ __launch_bounds__(256) void gather1_kernel(const int* __restrict__ rowptr,
                                                      const int* __restrict__ srcs,
                                                      const __half* __restrict__ hw1h,
                                                      const float* __restrict__ dinv,
                                                      const float* __restrict__ b1,
                                                      float* __restrict__ h) {
    int n = blockIdx.x * 4 + (threadIdx.x >> 6);
    int lane = threadIdx.x & 63;
    if (n >= N_NODES) return;
    int s = __builtin_amdgcn_readfirstlane(rowptr[n]);
    int e = __builtin_amdgcn_readfirstlane(rowptr[n + 1]);
    const __half* hb = hw1h + lane;     // lane-offset base; rows are 64 halves
    float acc = 0.f;
    int j = s;
    for (; j + 16 <= e; j += 16) {
        int i0 = srcs[j + 0],  i1 = srcs[j + 1],  i2 = srcs[j + 2],  i3 = srcs[j + 3];
        int i4 = srcs[j + 4],  i5 = srcs[j + 5],  i6 = srcs[j + 6],  i7 = srcs[j + 7];
        int i8 = srcs[j + 8],  i9 = srcs[j + 9],  iA = srcs[j + 10], iB = srcs[j + 11];
        int iC = srcs[j + 12], iD = srcs[j + 13], iE = srcs[j + 14], iF = srcs[j + 15];
        float v0 = __half2float(hb[(size_t)i0 << 6]);
        float v1 = __half2float(hb[(size_t)i1 << 6]);
        float v2 = __half2float(hb[(size_t)i2 << 6]);
        float v3 = __half2float(hb[(size_t)i3 << 6]);
        float v4 = __half2float(hb[(size_t)i4 << 6]);
        float v5 = __half2float(hb[(size_t)i5 << 6]);
        float v6 = __half2float(hb[(size_t)i6 << 6]);
        float v7 = __half2float(hb[(size_t)i7 << 6]);
        float v8 = __half2float(hb[(size_t)i8 << 6]);
        float v9 = __half2float(hb[(size_t)i9 << 6]);
        float vA = __half2float(hb[(size_t)iA << 6]);
        float vB = __half2float(hb[(size_t)iB << 6]);
        float vC = __half2float(hb[(size_t)iC << 6]);
        float vD = __half2float(hb[(size_t)iD << 6]);
        float vE = __half2float(hb[(size_t)iE << 6]);
        float vF = __half2float(hb[(size_t)iF << 6]);
        acc += (((v0 + v1) + (v2 + v3)) + ((v4 + v5) + (v6 + v7)))
             + (((v8 + v9) + (vA + vB)) + ((vC + vD) + (vE + vF)));
    }
    for (; j + 4 <= e; j += 4) {
        int i0 = srcs[j], i1 = srcs[j + 1], i2 = srcs[j + 2], i3 = srcs[j + 3];
        float v0 = __half2float(hb[(size_t)i0 << 6]);
        float v1 = __half2float(hb[(size_t)i1 << 6]);
        float v2 = __half2float(hb[(size_t)i2 << 6]);
        float v3 = __half2float(hb[(size_t)i3 << 6]);
        acc += (v0 + v1) + (v2 + v3);
    }
    for (; j < e; ++j) acc += __half2float(hb[(size_t)srcs[j] << 6]);
    float d = dinv[n];
    float v = fmaf(d, acc + __half2float(hb[(size_t)n << 6]), b1[lane]);
    h[(size_t)n * F_MID + lane] = fmaxf(v, 0.f);
}

// ---------------- GEMM2: hw2h = fp16( (h @ W2) * dinv[row] ), rows padded 40 -> 64 halves ----

__global__ __launch_bounds__(256) void gemm2_kernel(const float* __restrict__ h,
                                                    const float* __restrict__ W2,
                                                    const float* __restrict__ dinv,
                                                    __half* __restrict__ hw2h) {
    __shared__ float sW[F_MID * F_OUT];  // 10 KB
    for (int i = threadIdx.x; i < F_MID * F_OUT; i += 256) sW[i] = W2[i];
    __syncthreads();
    int idx = blockIdx.x * 256 + threadIdx.x;      // over N_NODES * 64 (padded rows)
    int r = idx >> 6;
    int c = idx & 63;
    float acc = 0.f;
    if (c < F_OUT) {
        const float* hr = h + (size_t)r * F_MID;
#pragma unroll
        for (int k = 0; k < F_MID; ++k) acc = fmaf(hr[k], sW[k * F_OUT + c], acc);
        acc *= dinv[r];
    }
    hw2h[idx] = __float2half(acc);                 // cols 40..63 = 0 (inert in gather)
}

// ---------------- gather2 + softmax (16-deep batches, fp16 padded rows) -----------

__global__ __launch_bounds__(256) void gather2_softmax_kernel(const int* __restrict__ rowptr,
                                                              const int* __restrict__ srcs,
                                                              const __half* __restrict__ hw2h,
                                                              const float* __restrict__ dinv,
                                                              const float* __restrict__ b2,
                                                              float* __restrict__ out) {
    int n = blockIdx.x * 4 + (threadIdx.x >> 6);
    int lane = threadIdx.x & 63;
    if (n >= N_NODES) return;
    int s = __builtin_amdgcn_readfirstlane(rowptr[n]);
    int e = __builtin_amdgcn_readfirstlane(rowptr[n + 1]);
    const __half* gb = hw2h + lane;                // rows are 64 halves (pad reads 0)
    float acc = 0.f;
    int j = s;
    for (; j + 16 <= e; j += 16) {
        int i0 = srcs[j + 0],  i1 = srcs[j + 1],  i2 = srcs[j + 2],  i3 = srcs[j + 3];
        int i4 = srcs[j + 4],  i5 = srcs[j + 5],  i6 = srcs[j + 6],  i7 = srcs[j + 7];
        int i8 = srcs[j + 8],  i9 = srcs[j + 9],  iA = srcs[j + 10], iB = srcs[j + 11];
        int iC = srcs[j + 12], iD = srcs[j + 13], iE = srcs[j + 14], iF = srcs[j + 15];
        float v0 = __half2float(gb[(size_t)i0 << 6]);
        float v1 = __half2float(gb[(size_t)i1 << 6]);
        float v2 = __half2float(gb[(size_t)i2 << 6]);
        float v3 = __half2float(gb[(size_t)i3 << 6]);
        float v4 = __half2float(gb[(size_t)i4 << 6]);
        float v5 = __half2float(gb[(size_t)i5 << 6]);
        float v6 = __half2float(gb[(size_t)i6 << 6]);
        float v7 = __half2float(gb[(size_t)i7 << 6]);
        float v8 = __half2float(gb[(size_t)i8 << 6]);
        float v9 = __half2float(gb[(size_t)i9 << 6]);
        float vA = __half2float(gb[(size_t)iA << 6]);
        float vB = __half2float(gb[(size_t)iB << 6]);
        float vC = __half2float(gb[(size_t)iC << 6]);
        float vD = __half2float(gb[(size_t)iD << 6]);
        float vE = __half2float(gb[(size_t)iE << 6]);
        float vF = __half2float(gb[(size_t)iF << 6]);
        acc += (((v0 + v1) + (v2 + v3)) + ((v4 + v5) + (v6 + v7)))
             + (((v8 + v9) + (vA + vB)) + ((vC + vD) + (vE + vF)));
    }
    for (; j + 4 <= e; j += 4) {
        int i0 = srcs[j], i1 = srcs[j + 1], i2 = srcs[j + 2], i3 = srcs[j + 3];
        float v0 = __half2float(gb[(size_t)i0 << 6]);
        float v1 = __half2float(gb[(size_t)i1 << 6]);
        float v2 = __half2float(gb[(size_t)i2 << 6]);
        float v3 = __half2float(gb[(size_t)i3 << 6]);
        acc += (v0 + v1) + (v2 + v3);
    }
    for (; j < e; ++j) acc += __half2float(gb[(size_t)srcs[j] << 6]);
    float d = dinv[n];
    float v = -3.402823466e38f;
    if (lane < F_OUT)
        v = fmaf(d, acc + __half2float(gb[(size_t)n << 6]), b2[lane]);
    float m = v;
#pragma unroll
    for (int off = 32; off > 0; off >>= 1) m = fmaxf(m, __shfl_xor(m, off, 64));
    float p = (lane < F_OUT) ? __expf(v - m) : 0.f;
    float su = p;
#pragma unroll
    for (int off = 32; off > 0; off >>= 1) su += __shfl_xor(su, off, 64);
    if (lane < F_OUT) out[(size_t)n * F_OUT + lane] = p / su;
}

// ---------------- launch ----------------

extern "C" void kernel_launch(void* const* d_in, const int* in_sizes, int n_in,
                              void* d_out, int out_size, void* d_ws, size_t ws_size,
                              hipStream_t stream) {
    const float* x  = (const float*)d_in[0];
    const int*   ei = (const int*)d_in[1];
    const float* W1 = (const float*)d_in[2];
    const float* b1 = (const float*)d_in[3];
    const float* W2 = (const float*)d_in[4];
    const float* b2 = (const float*)d_in[5];
    float* out = (float*)d_out;

    char* ws = (char*)d_ws;
    size_t off = 0;
    auto alloc = [&](size_t bytes) -> void* {
        void* p = ws + off;
        off += (bytes + 255) & ~(size_t)255;
        return p;
    };
    int*    counts = (int*)   alloc(NCOUNT * sizeof(int));
    int*    bsum   = (int*)   alloc(NSLICE * sizeof(int));
    int*    choff  = (int*)   alloc(NCOUNT * sizeof(int));
    int*    pairs  = (int*)   alloc((size_t)N_EDGES * sizeof(int));
    int*    rowptr = (int*)   alloc((N_NODES + 1) * sizeof(int));
    float*  dinv   = (float*) alloc(N_NODES * sizeof(float));
    int*    srcs   = (int*)   alloc((size_t)N_EDGES * sizeof(int));
    __half* hw1h   = (__half*)alloc((size_t)N_NODES * F_MID * sizeof(__half));
    float*  h      = (float*) alloc((size_t)N_NODES * F_MID * sizeof(float));
    __half* hw2h   = (__half*)alloc((size_t)N_NODES * F_MID * sizeof(__half));

    hipMemsetAsync(bsum, 0, NSLICE * sizeof(int), stream);
    bucket_count  <<<PCHUNKS, 256, 0, stream>>>(ei, counts, bsum);
    sc_scan       <<<NSLICE, 256, 0, stream>>>(counts, bsum, choff);
    bucket_scatter<<<PCHUNKS, 256, 0, stream>>>(ei, choff, pairs);
    slice_csr     <<<NSLICE, 256, 0, stream>>>(pairs, choff, rowptr, dinv, srcs);
    gemm1_kernel  <<<(N_NODES + 63) / 64, 256, 0, stream>>>(x, W1, dinv, hw1h);
    gather1_kernel<<<(N_NODES + 3) / 4, 256, 0, stream>>>(rowptr, srcs, hw1h, dinv, b1, h);
    gemm2_kernel  <<<(N_NODES * F_MID) / 256, 256, 0, stream>>>(h, W2, dinv, hw2h);
    gather2_softmax_kernel<<<(N_NODES + 3) / 4, 256, 0, stream>>>(rowptr, srcs, hw2h, dinv, b2, out);
}